// Round 2
// baseline (141.804 us; speedup 1.0000x reference)
//
#include <hip/hip_runtime.h>

#define DIM 256
#define BATCH 131072
#define BM 64            // rows per block (8 waves: 2 row-groups x 4 col-groups)
#define NT 8             // K-steps of 32 (DIM/32)

typedef __attribute__((ext_vector_type(8))) short s16x8;          // 8 bf16 (4 VGPRs)
typedef __attribute__((ext_vector_type(8))) unsigned short u16x8; // 16B
typedef __attribute__((ext_vector_type(4))) float f32x4;

static __device__ __forceinline__ unsigned short f2bf(float f) {
    unsigned int u = __builtin_bit_cast(unsigned int, f);
    u = (u + 0x7FFFu + ((u >> 16) & 1u)) >> 16;   // round-to-nearest-even
    return (unsigned short)u;
}

// ---- fused: m = l@u ; w = p@m (row permutation) ; wbt[d][k] = bf16(w[d][k]) ----
__global__ void lu_perm(const float* __restrict__ l, const float* __restrict__ u,
                        const float* __restrict__ p, unsigned short* __restrict__ wbt) {
    __shared__ float sL[DIM];
    __shared__ int dest;
    const int i = blockIdx.x, j = threadIdx.x;
    sL[j] = l[i * DIM + j];
    // row i of (l@u) becomes row d of w where p[d][i] == 1 (p is a permutation)
    if (p[j * DIM + i] != 0.0f) dest = j;
    __syncthreads();
    float s0 = 0.f, s1 = 0.f, s2 = 0.f, s3 = 0.f;
    #pragma unroll 4
    for (int k = 0; k < DIM; k += 4) {
        s0 = fmaf(sL[k + 0], u[(k + 0) * DIM + j], s0);
        s1 = fmaf(sL[k + 1], u[(k + 1) * DIM + j], s1);
        s2 = fmaf(sL[k + 2], u[(k + 2) * DIM + j], s2);
        s3 = fmaf(sL[k + 3], u[(k + 3) * DIM + j], s3);
    }
    wbt[dest * DIM + j] = f2bf((s0 + s1) + (s2 + s3));
}

// ---------------- log_det = sum log|diag(u)| ----------------
__global__ void logdet_kernel(const float* __restrict__ u, float* __restrict__ out) {
    const int i = threadIdx.x;
    float v = logf(fabsf(u[i * DIM + i]));
    #pragma unroll
    for (int o = 32; o; o >>= 1) v += __shfl_down(v, o, 64);
    __shared__ float partial[4];
    if ((i & 63) == 0) partial[i >> 6] = v;
    __syncthreads();
    if (i == 0) out[0] = (partial[0] + partial[1]) + (partial[2] + partial[3]);
}

// ---------------- y = x @ w^T, barrier-free streaming MFMA ----------------
// No LDS, no __syncthreads: A frags read straight from global (full-line
// coalesced across the wave), B frags from L2-resident wbt. Full unroll lets
// the compiler pipeline all loads; latency hidden by 16 waves/CU of
// independent streams.
__global__ __launch_bounds__(512, 4) void gemm_xwT(const float* __restrict__ x,
                                                   const unsigned short* __restrict__ wbt,
                                                   float* __restrict__ y) {
    const int t    = threadIdx.x;
    const int lane = t & 63;
    const int wid  = t >> 6;       // 0..7
    const int wr   = wid >> 2;     // 0..1 : 32-row half
    const int wc   = wid & 3;      // 0..3 : 64-col group
    const int lr   = lane & 15;
    const int lg   = lane >> 4;
    const long row0 = (long)blockIdx.x * BM;

    // per-lane bases (m adds 16*DIM floats; n adds 16*DIM shorts; ks adds 32)
    const float*          xa = x   + (row0 + wr * 32 + lr) * DIM + lg * 8;
    const unsigned short* bb = wbt + (wc * 64 + lr) * DIM + lg * 8;

    f32x4 acc[2][4];
    #pragma unroll
    for (int m = 0; m < 2; m++)
        #pragma unroll
        for (int n = 0; n < 4; n++) acc[m][n] = (f32x4){0.f, 0.f, 0.f, 0.f};

    #pragma unroll
    for (int ks = 0; ks < NT; ++ks) {
        const int k0 = ks * 32;
        s16x8 af[2];
        s16x8 bfr[4];
        #pragma unroll
        for (int m = 0; m < 2; m++) {
            const float* srcp = xa + (long)m * 16 * DIM + k0;
            const float4 v0 = *(const float4*)(srcp);
            const float4 v1 = *(const float4*)(srcp + 4);
            af[m] = (s16x8){ (short)f2bf(v0.x), (short)f2bf(v0.y),
                             (short)f2bf(v0.z), (short)f2bf(v0.w),
                             (short)f2bf(v1.x), (short)f2bf(v1.y),
                             (short)f2bf(v1.z), (short)f2bf(v1.w) };
        }
        #pragma unroll
        for (int n = 0; n < 4; n++) {
            const u16x8 w = *(const u16x8*)(bb + n * 16 * DIM + k0);
            bfr[n] = __builtin_bit_cast(s16x8, w);
        }
        #pragma unroll
        for (int m = 0; m < 2; m++)
            #pragma unroll
            for (int n = 0; n < 4; n++)
                acc[m][n] = __builtin_amdgcn_mfma_f32_16x16x32_bf16(af[m], bfr[n], acc[m][n], 0, 0, 0);
    }

    // epilogue: C/D layout col = lane&15, row = (lane>>4)*4 + j (m89-verified)
    #pragma unroll
    for (int m = 0; m < 2; m++) {
        const long gr0 = row0 + wr * 32 + m * 16 + lg * 4;
        #pragma unroll
        for (int n = 0; n < 4; n++) {
            const int gc = wc * 64 + n * 16 + lr;
            #pragma unroll
            for (int j = 0; j < 4; j++)
                y[(gr0 + j) * DIM + gc] = acc[m][n][j];
        }
    }
}

extern "C" void kernel_launch(void* const* d_in, const int* in_sizes, int n_in,
                              void* d_out, int out_size, void* d_ws, size_t ws_size,
                              hipStream_t stream) {
    const float* x = (const float*)d_in[0];
    const float* p = (const float*)d_in[1];
    const float* l = (const float*)d_in[2];
    const float* u = (const float*)d_in[3];
    float* out = (float*)d_out;

    unsigned short* wbt = (unsigned short*)d_ws;   // 128 KB bf16 w (row-major)

    lu_perm<<<DIM, DIM, 0, stream>>>(l, u, p, wbt);
    logdet_kernel<<<1, DIM, 0, stream>>>(u, out + (size_t)BATCH * DIM);
    gemm_xwT<<<BATCH / BM, 512, 0, stream>>>(x, wbt, out);
}

// Round 3
// 66.764 us; speedup vs baseline: 2.1240x; 2.1240x over previous
//
#include <hip/hip_runtime.h>

#define DIM 256
#define BATCH 131072
#define BM 64            // rows per block; 4 waves, each 64 rows x 64 cols
#define NT 8             // K-steps of 32

typedef __attribute__((ext_vector_type(8))) short s16x8;          // 8 bf16 (4 VGPRs)
typedef __attribute__((ext_vector_type(8))) unsigned short u16x8; // 16B
typedef __attribute__((ext_vector_type(4))) float f32x4;

static __device__ __forceinline__ unsigned short f2bf(float f) {
    unsigned int u = __builtin_bit_cast(unsigned int, f);
    u = (u + 0x7FFFu + ((u >> 16) & 1u)) >> 16;   // round-to-nearest-even
    return (unsigned short)u;
}

static __device__ __forceinline__ s16x8 cvt8(const float4 a, const float4 b) {
    return (s16x8){ (short)f2bf(a.x), (short)f2bf(a.y), (short)f2bf(a.z), (short)f2bf(a.w),
                    (short)f2bf(b.x), (short)f2bf(b.y), (short)f2bf(b.z), (short)f2bf(b.w) };
}

// ---- fused: m = l@u ; w = p@m ; store bf16 w in MFMA-fragment order ----
// frag order: elem (d,k) -> ((d>>4)*8 + (k>>5))*512 + (((k>>3)&3)*16 + (d&15))*8 + (k&7)
__global__ void lu_perm(const float* __restrict__ l, const float* __restrict__ u,
                        const float* __restrict__ p, unsigned short* __restrict__ wpk) {
    __shared__ float sL[DIM];
    __shared__ int dest;
    const int i = blockIdx.x, j = threadIdx.x;
    sL[j] = l[i * DIM + j];
    if (p[j * DIM + i] != 0.0f) dest = j;   // row i of l@u -> row dest of w
    __syncthreads();
    float s0 = 0.f, s1 = 0.f, s2 = 0.f, s3 = 0.f;
    #pragma unroll 4
    for (int k = 0; k < DIM; k += 4) {
        s0 = fmaf(sL[k + 0], u[(k + 0) * DIM + j], s0);
        s1 = fmaf(sL[k + 1], u[(k + 1) * DIM + j], s1);
        s2 = fmaf(sL[k + 2], u[(k + 2) * DIM + j], s2);
        s3 = fmaf(sL[k + 3], u[(k + 3) * DIM + j], s3);
    }
    const int d = dest;
    const int idx = ((d >> 4) * 8 + (j >> 5)) * 512 + (((j >> 3) & 3) * 16 + (d & 15)) * 8 + (j & 7);
    wpk[idx] = f2bf((s0 + s1) + (s2 + s3));
}

// ---------------- log_det = sum log|diag(u)| ----------------
__global__ void logdet_kernel(const float* __restrict__ u, float* __restrict__ out) {
    const int i = threadIdx.x;
    float v = logf(fabsf(u[i * DIM + i]));
    #pragma unroll
    for (int o = 32; o; o >>= 1) v += __shfl_down(v, o, 64);
    __shared__ float partial[4];
    if ((i & 63) == 0) partial[i >> 6] = v;
    __syncthreads();
    if (i == 0) out[0] = (partial[0] + partial[1]) + (partial[2] + partial[3]);
}

// ---------------- y = x @ w^T ----------------
// A: coalesced global->reg (32B contiguous/thread) -> f2bf -> ds_write_b128 into
//    fragment-order LDS (bijective lane permutation: conflict-free both sides).
// B: fully-coalesced 16B/lane loads from the frag-packed, L2-resident wpk.
// Pipeline: depth-2 A reg-prefetch, depth-1 B reg-prefetch, convert+write after
// the MFMA phase (T14 split), ONE barrier per K-step, fully unrolled.
__global__ __launch_bounds__(256, 3) void gemm_xwT(const float* __restrict__ x,
                                                   const unsigned short* __restrict__ wpk,
                                                   float* __restrict__ y) {
    __shared__ unsigned short sA[2][BM * 32];   // 2 x 4 KB, fragment order

    const int t    = threadIdx.x;
    const int lane = t & 63;
    const int wc   = t >> 6;        // 0..3 : 64-col group
    const int lr   = lane & 15;
    const int lg   = lane >> 4;
    const long row0 = (long)blockIdx.x * BM;

    // A staging: thread t loads 32B contiguous: row sr, f32-cols sc..sc+8
    const int sr = t >> 2;
    const int sc = (t & 3) * 8;
    const float* asrc = x + (row0 + sr) * DIM + sc;
    // frag-order dest (elems): m-block (sr>>4), lane' = (t&3)*16 + (sr&15)
    unsigned short* adst = &sA[0][(sr >> 4) * 512 + ((t & 3) * 16 + (sr & 15)) * 8];
    const int bufoff = BM * 32;     // elems between buffers

    const unsigned short* bbase = wpk + (wc * 4) * 8 * 512 + lane * 8;  // + (n*8+ks)*512

    f32x4 acc[4][4];
    #pragma unroll
    for (int mi = 0; mi < 4; mi++)
        #pragma unroll
        for (int n = 0; n < 4; n++) acc[mi][n] = (f32x4){0.f, 0.f, 0.f, 0.f};

    // ---- prologue: A(0)->S0, A(1)->S1, B(0)->BF0; write buf0 ----
    float4 sa0 = *(const float4*)(asrc);
    float4 sa1 = *(const float4*)(asrc + 4);
    float4 sb0 = *(const float4*)(asrc + 32);
    float4 sb1 = *(const float4*)(asrc + 36);
    s16x8 bf0[4], bf1[4];
    #pragma unroll
    for (int n = 0; n < 4; n++)
        bf0[n] = __builtin_bit_cast(s16x8, *(const u16x8*)(bbase + (n * 8 + 0) * 512));
    *(s16x8*)adst = cvt8(sa0, sa1);
    __syncthreads();

    #pragma unroll
    for (int ks = 0; ks < NT; ++ks) {
        // issue A loads for ks+2 into the set freed last iter
        if (ks < NT - 2) {
            const float* nsrc = asrc + (ks + 2) * 32;
            if ((ks & 1) == 0) { sa0 = *(const float4*)(nsrc); sa1 = *(const float4*)(nsrc + 4); }
            else               { sb0 = *(const float4*)(nsrc); sb1 = *(const float4*)(nsrc + 4); }
        }
        // issue B loads for ks+1
        if (ks < NT - 1) {
            #pragma unroll
            for (int n = 0; n < 4; n++) {
                const s16x8 v = __builtin_bit_cast(s16x8, *(const u16x8*)(bbase + (n * 8 + ks + 1) * 512));
                if ((ks & 1) == 0) bf1[n] = v; else bf0[n] = v;
            }
        }
        // A frags from LDS (conflict-free b128)
        const unsigned short* abuf = &sA[0][(ks & 1) * bufoff];
        s16x8 af[4];
        #pragma unroll
        for (int mi = 0; mi < 4; mi++)
            af[mi] = *(const s16x8*)(abuf + mi * 512 + lane * 8);
        // MFMA
        #pragma unroll
        for (int mi = 0; mi < 4; mi++)
            #pragma unroll
            for (int n = 0; n < 4; n++)
                acc[mi][n] = __builtin_amdgcn_mfma_f32_16x16x32_bf16(
                    af[mi], (ks & 1) ? bf1[n] : bf0[n], acc[mi][n], 0, 0, 0);
        // convert + write A(ks+1) to the other buffer (T14: after compute)
        if (ks < NT - 1) {
            unsigned short* wdst = adst + ((ks + 1) & 1) * bufoff;
            *(s16x8*)wdst = ((ks & 1) == 0) ? cvt8(sb0, sb1) : cvt8(sa0, sa1);
        }
        __syncthreads();
    }

    // ---- epilogue: C/D layout col=lane&15, row=(lane>>4)*4+j ----
    #pragma unroll
    for (int mi = 0; mi < 4; mi++) {
        const long gr0 = row0 + mi * 16 + lg * 4;
        #pragma unroll
        for (int n = 0; n < 4; n++) {
            const int gc = wc * 64 + n * 16 + lr;
            #pragma unroll
            for (int j = 0; j < 4; j++)
                y[(gr0 + j) * DIM + gc] = acc[mi][n][j];
        }
    }
}

extern "C" void kernel_launch(void* const* d_in, const int* in_sizes, int n_in,
                              void* d_out, int out_size, void* d_ws, size_t ws_size,
                              hipStream_t stream) {
    const float* x = (const float*)d_in[0];
    const float* p = (const float*)d_in[1];
    const float* l = (const float*)d_in[2];
    const float* u = (const float*)d_in[3];
    float* out = (float*)d_out;

    unsigned short* wpk = (unsigned short*)d_ws;   // 128 KB frag-packed bf16 w

    lu_perm<<<DIM, DIM, 0, stream>>>(l, u, p, wpk);
    logdet_kernel<<<1, DIM, 0, stream>>>(u, out + (size_t)BATCH * DIM);
    gemm_xwT<<<BATCH / BM, 256, 0, stream>>>(x, wpk, out);
}

// Round 4
// 62.938 us; speedup vs baseline: 2.2531x; 1.0608x over previous
//
#include <hip/hip_runtime.h>

#define DIM 256
#define BATCH 131072
#define BM 64            // rows per block; 4 waves, each: all 64 rows x its 64-col group

typedef __attribute__((ext_vector_type(8))) short s16x8;          // 8 bf16 (4 VGPRs)
typedef __attribute__((ext_vector_type(8))) unsigned short u16x8; // 16B
typedef __attribute__((ext_vector_type(4))) float f32x4;

static __device__ __forceinline__ unsigned short f2bf(float f) {
    unsigned int u = __builtin_bit_cast(unsigned int, f);
    u = (u + 0x7FFFu + ((u >> 16) & 1u)) >> 16;   // round-to-nearest-even
    return (unsigned short)u;
}

static __device__ __forceinline__ s16x8 cvt8(const float4 a, const float4 b) {
    return (s16x8){ (short)f2bf(a.x), (short)f2bf(a.y), (short)f2bf(a.z), (short)f2bf(a.w),
                    (short)f2bf(b.x), (short)f2bf(b.y), (short)f2bf(b.z), (short)f2bf(b.w) };
}

// ---- fused: m = l@u ; w = p@m ; store bf16 w in MFMA-fragment order ----
// frag order: elem (d,k) -> ((d>>4)*8 + (k>>5))*512 + (((k>>3)&3)*16 + (d&15))*8 + (k&7)
__global__ void lu_perm(const float* __restrict__ l, const float* __restrict__ u,
                        const float* __restrict__ p, unsigned short* __restrict__ wpk) {
    __shared__ float sL[DIM];
    __shared__ int dest;
    const int i = blockIdx.x, j = threadIdx.x;
    sL[j] = l[i * DIM + j];
    if (p[j * DIM + i] != 0.0f) dest = j;   // row i of l@u -> row dest of w
    __syncthreads();
    float s0 = 0.f, s1 = 0.f, s2 = 0.f, s3 = 0.f;
    #pragma unroll 4
    for (int k = 0; k < DIM; k += 4) {
        s0 = fmaf(sL[k + 0], u[(k + 0) * DIM + j], s0);
        s1 = fmaf(sL[k + 1], u[(k + 1) * DIM + j], s1);
        s2 = fmaf(sL[k + 2], u[(k + 2) * DIM + j], s2);
        s3 = fmaf(sL[k + 3], u[(k + 3) * DIM + j], s3);
    }
    const int d = dest;
    const int idx = ((d >> 4) * 8 + (j >> 5)) * 512 + (((j >> 3) & 3) * 16 + (d & 15)) * 8 + (j & 7);
    wpk[idx] = f2bf((s0 + s1) + (s2 + s3));
}

// ---------------- log_det = sum log|diag(u)| ----------------
__global__ void logdet_kernel(const float* __restrict__ u, float* __restrict__ out) {
    const int i = threadIdx.x;
    float v = logf(fabsf(u[i * DIM + i]));
    #pragma unroll
    for (int o = 32; o; o >>= 1) v += __shfl_down(v, o, 64);
    __shared__ float partial[4];
    if ((i & 63) == 0) partial[i >> 6] = v;
    __syncthreads();
    if (i == 0) out[0] = (partial[0] + partial[1]) + (partial[2] + partial[3]);
}

// ---------------- y = x @ w^T ----------------
// Single-shot A staging (32 KB, frag-order, XOR-swizzled: every ds op is a
// lane-permuted contiguous 1KB access -> conflict-free). ONE barrier, then 8
// barrier-free K-steps {ds_read A, L2 B prefetch, MFMA}. Epilogue transposes
// acc through LDS (reused A buffer) to emit full-row float4 stores.
__global__ __launch_bounds__(256, 3) void gemm_xwT(const float* __restrict__ x,
                                                   const unsigned short* __restrict__ wpk,
                                                   float* __restrict__ y) {
    __shared__ unsigned short sA[4 * 8 * 512];   // 32 KB: [mb][ks][lane''][8]

    const int t    = threadIdx.x;
    const int lane = t & 63;
    const int wc   = t >> 6;        // 0..3 : 64-col group (also mb for staging)
    const int lr   = lane & 15;
    const int lg   = lane >> 4;
    const long row0 = (long)blockIdx.x * BM;

    // ---- single-shot A staging: thread t covers row sr, cols kq*8 + q*32 ----
    const int sr  = t >> 2;         // 0..63
    const int kq  = t & 3;
    const int r15 = sr & 15;
    const int mb  = t >> 6;         // == sr>>4 == wave id
    const float* asrc = x + (row0 + sr) * DIM + kq * 8;
    const int lpx = (kq * 16 + r15) ^ (kq << 1);   // lane' ^ lane'-dependent XOR part
    #pragma unroll
    for (int q = 0; q < 8; ++q) {   // q == ks for this thread's writes
        const float4 v0 = *(const float4*)(asrc + q * 32);
        const float4 v1 = *(const float4*)(asrc + q * 32 + 4);
        *(s16x8*)&sA[(mb * 8 + q) * 512 + (lpx ^ q) * 8] = cvt8(v0, v1);
    }

    // ---- B: frag-packed, L2-resident; double-buffered register prefetch ----
    const unsigned short* bbase = wpk + wc * 4 * 8 * 512 + lane * 8;  // + (n*8+ks)*512
    const int lx = lane ^ ((lane >> 4) << 1);      // read-side XOR (ks applied per step)

    f32x4 acc[4][4];
    #pragma unroll
    for (int mi = 0; mi < 4; mi++)
        #pragma unroll
        for (int n = 0; n < 4; n++) acc[mi][n] = (f32x4){0.f, 0.f, 0.f, 0.f};

    s16x8 bf[2][4];
    #pragma unroll
    for (int n = 0; n < 4; n++)
        bf[0][n] = __builtin_bit_cast(s16x8, *(const u16x8*)(bbase + n * 8 * 512));

    __syncthreads();   // the ONLY pre-compute barrier

    #pragma unroll
    for (int ks = 0; ks < 8; ++ks) {
        if (ks < 7) {
            #pragma unroll
            for (int n = 0; n < 4; n++)
                bf[(ks + 1) & 1][n] = __builtin_bit_cast(s16x8,
                    *(const u16x8*)(bbase + (n * 8 + ks + 1) * 512));
        }
        s16x8 af[4];
        #pragma unroll
        for (int mi = 0; mi < 4; mi++)
            af[mi] = *(const s16x8*)&sA[(mi * 8 + ks) * 512 + (lx ^ ks) * 8];
        #pragma unroll
        for (int mi = 0; mi < 4; mi++)
            #pragma unroll
            for (int n = 0; n < 4; n++)
                acc[mi][n] = __builtin_amdgcn_mfma_f32_16x16x32_bf16(
                    af[mi], bf[ks & 1][n], acc[mi][n], 0, 0, 0);
    }

    __syncthreads();   // all waves done reading sA before reuse

    // ---- epilogue: per-wave LDS transpose -> full-row float4 stores ----
    float* ep = (float*)sA + wc * 1088;            // 16 x 68 f32 region per wave
    #pragma unroll
    for (int mi = 0; mi < 4; ++mi) {
        #pragma unroll
        for (int n = 0; n < 4; n++)
            #pragma unroll
            for (int j = 0; j < 4; j++)
                ep[(lg * 4 + j) * 68 + n * 16 + lr] = acc[mi][n][j];
        // per-wave in-order DS: reads below see this wave's writes
        #pragma unroll
        for (int it = 0; it < 4; ++it) {
            const int row = it * 4 + lg;           // 0..15
            const float4 v = *(const float4*)&ep[row * 68 + lr * 4];
            *(float4*)&y[(row0 + mi * 16 + row) * DIM + wc * 64 + lr * 4] = v;
        }
    }
}

extern "C" void kernel_launch(void* const* d_in, const int* in_sizes, int n_in,
                              void* d_out, int out_size, void* d_ws, size_t ws_size,
                              hipStream_t stream) {
    const float* x = (const float*)d_in[0];
    const float* p = (const float*)d_in[1];
    const float* l = (const float*)d_in[2];
    const float* u = (const float*)d_in[3];
    float* out = (float*)d_out;

    unsigned short* wpk = (unsigned short*)d_ws;   // 128 KB frag-packed bf16 w

    lu_perm<<<DIM, DIM, 0, stream>>>(l, u, p, wpk);
    logdet_kernel<<<1, DIM, 0, stream>>>(u, out + (size_t)BATCH * DIM);
    gemm_xwT<<<BATCH / BM, 256, 0, stream>>>(x, wpk, out);
}